// Round 9
// baseline (873.692 us; speedup 1.0000x reference)
//
#include <hip/hip_runtime.h>

#define NN 100000
#define NE 1600000
#define DD 64
#define NGRP 6250   // NN/16
#define NBGRU 1563  // ceil(NGRP/4)
#define NBKT 391    // buckets of 256 dst nodes (ceil(NN/256))
#define BCAP 4608   // per-bucket edge capacity: mean 4092, sd 64 -> +8 sigma
#define BCH  4096   // edges per bin_k block
#define NBIN 391    // ceil(NE/BCH)
#define OVCAP 4096  // overflow capacity (never hit in practice)

typedef __attribute__((ext_vector_type(8))) short short8_t;
typedef __attribute__((ext_vector_type(4))) float f32x4;

__device__ __forceinline__ float fsig(float x) {
    return __fdividef(1.0f, 1.0f + __expf(-x));
}
__device__ __forceinline__ float ftanh(float x) {
    return __fdividef(2.0f, 1.0f + __expf(-2.0f * x)) - 1.0f;
}
__device__ __forceinline__ unsigned int bf16rne(float a) {
    unsigned int u = __float_as_uint(a);
    return (u + 0x7fffu + ((u >> 16) & 1u)) >> 16;
}
__device__ __forceinline__ short8_t pack8(float4 a, float4 b) {
    short8_t r;
    r[0] = (short)bf16rne(a.x); r[1] = (short)bf16rne(a.y);
    r[2] = (short)bf16rne(a.z); r[3] = (short)bf16rne(a.w);
    r[4] = (short)bf16rne(b.x); r[5] = (short)bf16rne(b.y);
    r[6] = (short)bf16rne(b.z); r[7] = (short)bf16rne(b.w);
    return r;
}

// ---- bin_k: LDS-staged bucket binning ----------------------------------
// Bucket b = dst>>8 (256 nodes per bucket). Payload (src | dlocal<<17, w).
// Per chunk of 4096 edges: count -> LDS scan -> stage ordered by bucket ->
// one global atomicAdd per bucket -> coalesced flush (runs of ~10 edges,
// written back-to-back by consecutive threads => L2 write-combines; write
// traffic ~= payload, not 8x like the old exact-CSR scatter).
__global__ __launch_bounds__(256) void bin_k(const int* __restrict__ src,
                                             const int* __restrict__ dst,
                                             const float* __restrict__ ew,
                                             unsigned* __restrict__ gcnt,
                                             uint2* __restrict__ binbuf,
                                             unsigned* __restrict__ ovcnt,
                                             uint2* __restrict__ ov_a,
                                             unsigned* __restrict__ ov_b) {
    __shared__ unsigned cnt[NBKT];
    __shared__ unsigned cur[NBKT];
    __shared__ unsigned offb[NBKT];
    __shared__ unsigned gbase[NBKT];
    __shared__ unsigned ssc[256];
    __shared__ uint2 stage[BCH];
    __shared__ unsigned short sbkt[BCH];

    const int t = threadIdx.x;
    const int e0 = blockIdx.x * BCH;
    const int M = min(BCH, NE - e0);

    for (int i = t; i < NBKT; i += 256) cnt[i] = 0;
    __syncthreads();

    // pass 1: count
    for (int i = t; i < M; i += 256) {
        const unsigned b = ((unsigned)dst[e0 + i]) >> 8;
        atomicAdd(&cnt[b], 1u);
    }
    __syncthreads();

    // exclusive scan of cnt[0..390] with 256 threads, two segments
    {
        const unsigned v0 = cnt[t];
        ssc[t] = v0;
        __syncthreads();
        for (int o = 1; o < 256; o <<= 1) {
            const unsigned tmp = (t >= o) ? ssc[t - o] : 0u;
            __syncthreads();
            ssc[t] += tmp;
            __syncthreads();
        }
        const unsigned ex0 = ssc[t] - v0;
        const unsigned segtot = ssc[255];
        __syncthreads();
        offb[t] = ex0;
        const unsigned v1 = (256 + t < NBKT) ? cnt[256 + t] : 0u;
        ssc[t] = v1;
        __syncthreads();
        for (int o = 1; o < 256; o <<= 1) {
            const unsigned tmp = (t >= o) ? ssc[t - o] : 0u;
            __syncthreads();
            ssc[t] += tmp;
            __syncthreads();
        }
        if (256 + t < NBKT) offb[256 + t] = ssc[t] - v1 + segtot;
    }
    // cursors
    cur[t] = offb[t];
    if (256 + t < NBKT) cur[256 + t] = offb[256 + t];
    __syncthreads();

    // pass 2: re-read edges (L2-hot), place into stage ordered by bucket
    for (int i = t; i < M; i += 256) {
        const int d = dst[e0 + i];
        const unsigned b = ((unsigned)d) >> 8;
        const unsigned p = atomicAdd(&cur[b], 1u);
        stage[p] = make_uint2((unsigned)src[e0 + i] | (((unsigned)(d & 255)) << 17),
                              __float_as_uint(ew[e0 + i]));
        sbkt[p] = (unsigned short)b;
    }
    __syncthreads();

    // per-bucket global base
    for (int i = t; i < NBKT; i += 256) {
        const unsigned c = cnt[i];
        gbase[i] = c ? atomicAdd(&gcnt[i], c) : 0u;
    }
    __syncthreads();

    // coalesced flush
    for (int i = t; i < M; i += 256) {
        const unsigned b = sbkt[i];
        const unsigned gp = gbase[b] + ((unsigned)i - offb[b]);
        if (gp < BCAP) {
            binbuf[b * BCAP + gp] = stage[i];
        } else {                                    // ~never: +8 sigma margin
            const unsigned op = atomicAdd(ovcnt, 1u);
            if (op < OVCAP) { ov_a[op] = stage[i]; ov_b[op] = b; }
        }
    }
}

// ---- bseg_k: bucket-local segment sum in LDS ---------------------------
// One block per bucket: 256 nodes x 64 ch accumulator tile (64 KB LDS).
// Each wave streams a quarter of the bucket's edges with the shfl-broadcast
// pattern; lanes accumulate via LDS float atomics (ds_add_f32). acc row
// addresses are 256B-contiguous per wave -> 2-way bank aliasing (free).
__global__ __launch_bounds__(256) void bseg_k(const float* __restrict__ h,
                                              const uint2* __restrict__ binbuf,
                                              const unsigned* __restrict__ gcnt,
                                              const unsigned* __restrict__ ovcnt,
                                              const uint2* __restrict__ ov_a,
                                              const unsigned* __restrict__ ov_b,
                                              float* __restrict__ hnew) {
    __shared__ float acc[256 * DD];   // 65536 B
    const int t = threadIdx.x;
    const int b = blockIdx.x;
    const int lane = t & 63;
    const int wid = t >> 6;

    const float4 z4 = make_float4(0.f, 0.f, 0.f, 0.f);
    for (int i = t; i < 256 * DD / 4; i += 256) ((float4*)acc)[i] = z4;
    __syncthreads();

    const unsigned cnt = min(gcnt[b], (unsigned)BCAP);
    const uint2* ep = binbuf + (unsigned)b * BCAP;
    const unsigned w0 = (cnt * (unsigned)wid) >> 2;
    const unsigned w1 = (cnt * (unsigned)(wid + 1)) >> 2;

    for (unsigned base = w0; base < w1; base += 64) {
        const unsigned m = min(64u, w1 - base);
        uint2 pr = make_uint2(0u, 0u);
        if ((unsigned)lane < m) pr = ep[base + lane];     // coalesced 8B/lane
        #pragma unroll 4
        for (int j = 0; j < (int)m; ++j) {
            const unsigned sx = (unsigned)__shfl((int)pr.x, j);
            const float    w  = __shfl(__uint_as_float(pr.y), j);
            const unsigned sn = sx & 0x1ffffu;            // src node (17 bits)
            const unsigned dl = sx >> 17;                 // dst local (8 bits)
            atomicAdd(&acc[(dl << 6) + lane], w * h[(sn << 6) + lane]);
        }
    }

    // overflow edges (cold: ovcnt == 0 in practice)
    const unsigned oc = min(*ovcnt, (unsigned)OVCAP);
    if (oc) {
        __syncthreads();
        if (wid == 0) {
            for (unsigned i = 0; i < oc; ++i) {
                if (ov_b[i] == (unsigned)b) {
                    const uint2 pr = ov_a[i];
                    const unsigned sn = pr.x & 0x1ffffu;
                    const unsigned dl = pr.x >> 17;
                    atomicAdd(&acc[(dl << 6) + lane],
                              __uint_as_float(pr.y) * h[(sn << 6) + lane]);
                }
            }
        }
    }
    __syncthreads();

    const int nbase = b << 8;
    for (int r = wid; r < 256; r += 4) {
        const int node = nbase + r;
        if (node < NN) hnew[(node << 6) + lane] = acc[(r << 6) + lane];
    }
}

// ---- Weight prep: pack Wih/Whh into MFMA B-fragment order (bf16) --------
__global__ __launch_bounds__(256) void wprep_k(const float* __restrict__ Wih,
                                               const float* __restrict__ Whh,
                                               unsigned* __restrict__ wfrag) {
    const int idx = blockIdx.x * 256 + threadIdx.x;  // 24 blocks * 256 = 6144
    const int row = idx >> 5;        // W row (= output col), 0..191
    const int k2  = idx & 31;        // k/2
    const int ct  = row >> 4;
    const int c   = row & 15;
    const int ks  = k2 >> 4;
    const int lhi = (k2 >> 2) & 3;   // (k>>3)&3
    const int lane = c + (lhi << 4);
    const int slot = k2 & 3;         // (k&7)>>1
    const int fo = (((ct << 1) + ks) << 8) + (lane << 2) + slot;
    const float2 wi = *(const float2*)(Wih + (row << 6) + (k2 << 1));
    const float2 wh = *(const float2*)(Whh + (row << 6) + (k2 << 1));
    wfrag[fo]            = bf16rne(wi.x) | (bf16rne(wi.y) << 16);
    wfrag[24 * 256 + fo] = bf16rne(wh.x) | (bf16rne(wh.y) << 16);
}

// ---- GRU cell via MFMA --------------------------------------------------
// One wave per 16-node group; 96 mfma_f32_16x16x32_bf16 per wave; no LDS.
// C layout (m89): col = lane&15, row = 4*(lane>>4) + reg.
__global__ __launch_bounds__(256) void gru_k(
    const float* hnew, const float* __restrict__ h,
    const unsigned* __restrict__ wfrag,
    const float* __restrict__ bih, const float* __restrict__ bhh,
    float* out)
{
    const int tid  = threadIdx.x;
    const int wid  = tid >> 6;
    const int lane = tid & 63;
    const int grp  = blockIdx.x * 4 + wid;
    if (grp >= NGRP) return;
    const int base = grp << 4;

    const int rA   = lane & 15;
    const int koff = (lane >> 4) << 3;

    const float* xr = hnew + ((base + rA) << 6);
    const float* hr = h    + ((base + rA) << 6);

    short8_t ax[2], ah[2];
    #pragma unroll
    for (int ks = 0; ks < 2; ++ks) {
        const float4 x0 = *(const float4*)(xr + ks * 32 + koff);
        const float4 x1 = *(const float4*)(xr + ks * 32 + koff + 4);
        const float4 h0 = *(const float4*)(hr + ks * 32 + koff);
        const float4 h1 = *(const float4*)(hr + ks * 32 + koff + 4);
        ax[ks] = pack8(x0, x1);
        ah[ks] = pack8(h0, h1);
    }

    f32x4 acc[24];
    #pragma unroll
    for (int i = 0; i < 24; ++i) acc[i] = (f32x4){0.f, 0.f, 0.f, 0.f};

    const unsigned* wf = wfrag + (lane << 2);
    #pragma unroll
    for (int ct = 0; ct < 12; ++ct) {
        const short8_t b0 = *(const short8_t*)(wf + (((ct << 1)     ) << 8));
        const short8_t b1 = *(const short8_t*)(wf + (((ct << 1) + 1) << 8));
        const short8_t c0 = *(const short8_t*)(wf + ((24 + (ct << 1)    ) << 8));
        const short8_t c1 = *(const short8_t*)(wf + ((24 + (ct << 1) + 1) << 8));
        acc[ct]      = __builtin_amdgcn_mfma_f32_16x16x32_bf16(ax[0], b0, acc[ct],      0, 0, 0);
        acc[ct]      = __builtin_amdgcn_mfma_f32_16x16x32_bf16(ax[1], b1, acc[ct],      0, 0, 0);
        acc[12 + ct] = __builtin_amdgcn_mfma_f32_16x16x32_bf16(ah[0], c0, acc[12 + ct], 0, 0, 0);
        acc[12 + ct] = __builtin_amdgcn_mfma_f32_16x16x32_bf16(ah[1], c1, acc[12 + ct], 0, 0, 0);
    }

    const int rnode = base + ((lane >> 4) << 2);
    const int c     = lane & 15;
    #pragma unroll
    for (int ct = 0; ct < 4; ++ct) {
        const int ch = (ct << 4) + c;
        const float brz = bih[ch] + bhh[ch];
        const float bzz = bih[64 + ch] + bhh[64 + ch];
        const float bin = bih[128 + ch];
        const float bhn = bhh[128 + ch];
        #pragma unroll
        for (int r = 0; r < 4; ++r) {
            const int node = rnode + r;
            const float rr = fsig(acc[ct][r] + acc[12 + ct][r] + brz);
            const float zz = fsig(acc[4 + ct][r] + acc[16 + ct][r] + bzz);
            const float hn = acc[20 + ct][r] + bhn;
            const float nn = ftanh(fmaf(rr, hn, acc[8 + ct][r] + bin));
            const float hv = h[(node << 6) + ch];
            out[(node << 6) + ch] = fmaf(zz, hv - nn, nn);  // (1-z)*n + z*h
        }
    }
}

extern "C" void kernel_launch(void* const* d_in, const int* in_sizes, int n_in,
                              void* d_out, int out_size, void* d_ws, size_t ws_size,
                              hipStream_t stream)
{
    const float* h   = (const float*)d_in[0];
    const float* ew  = (const float*)d_in[1];
    const float* Wih = (const float*)d_in[2];
    const float* Whh = (const float*)d_in[3];
    const float* bih = (const float*)d_in[4];
    const float* bhh = (const float*)d_in[5];
    const int*   src = (const int*)d_in[6];
    const int*   dst = (const int*)d_in[7];
    float* out = (float*)d_out;

    // ws layout (~14.5 MB total)
    char* ws = (char*)d_ws;
    unsigned* gcnt   = (unsigned*)(ws);                    //   2,048 B (391 used)
    unsigned* ovcnt  = (unsigned*)(ws + 2048);             //      64 B
    unsigned* wfrag  = (unsigned*)(ws + 2112);             //  49,152 B
    uint2*    binbuf = (uint2*)   (ws + 65536);            // 391*4608*8 = 14,413,824 B
    uint2*    ov_a   = (uint2*)   (ws + 65536 + 14413824); //  32,768 B
    unsigned* ov_b   = (unsigned*)(ws + 65536 + 14413824 + 32768); // 16,384 B

    hipMemsetAsync(ws, 0, 2112, stream);                   // gcnt + ovcnt
    wprep_k<<<24, 256, 0, stream>>>(Wih, Whh, wfrag);
    bin_k  <<<NBIN, 256, 0, stream>>>(src, dst, ew, gcnt, binbuf, ovcnt, ov_a, ov_b);
    bseg_k <<<NBKT, 256, 0, stream>>>(h, binbuf, gcnt, ovcnt, ov_a, ov_b, out); // out = hnew
    gru_k  <<<NBGRU, 256, 0, stream>>>(out, h, wfrag, bih, bhh, out);
}

// Round 11
// 386.617 us; speedup vs baseline: 2.2598x; 2.2598x over previous
//
#include <hip/hip_runtime.h>

#define NN 100000
#define NE 1600000
#define DD 64
#define NB1 391    // ceil(NN/256)
#define NGRP 6250  // NN/16
#define NBGRU 1563 // ceil(NGRP/4)

typedef __attribute__((ext_vector_type(8))) short short8_t;
typedef __attribute__((ext_vector_type(4))) float f32x4;

__device__ __forceinline__ float fsig(float x) {
    return __fdividef(1.0f, 1.0f + __expf(-x));
}
__device__ __forceinline__ float ftanh(float x) {
    return __fdividef(2.0f, 1.0f + __expf(-2.0f * x)) - 1.0f;
}
__device__ __forceinline__ unsigned int bf16rne(float a) {
    unsigned int u = __float_as_uint(a);
    return (u + 0x7fffu + ((u >> 16) & 1u)) >> 16;
}
__device__ __forceinline__ short8_t pack8(float4 a, float4 b) {
    short8_t r;
    r[0] = (short)bf16rne(a.x); r[1] = (short)bf16rne(a.y);
    r[2] = (short)bf16rne(a.z); r[3] = (short)bf16rne(a.w);
    r[4] = (short)bf16rne(b.x); r[5] = (short)bf16rne(b.y);
    r[6] = (short)bf16rne(b.z); r[7] = (short)bf16rne(b.w);
    return r;
}

// ---- Sort phase: build CSR (edges grouped by dst) -----------------------
// deg/cursor are 400KB -> L2-resident atomics; 3.2M total atomics.
// (Measured-good pipeline from the 411us run; bseg/bin bucket scheme was
// 733us due to 391-block grid starvation -> reverted.)

__global__ __launch_bounds__(256) void hist_k(const int* __restrict__ dst,
                                              unsigned* __restrict__ deg) {
    const int e = blockIdx.x * 256 + threadIdx.x;   // grid covers NE exactly
    atomicAdd(&deg[dst[e]], 1u);
}

__global__ __launch_bounds__(256) void scan1_k(const unsigned* __restrict__ deg,
                                               unsigned* __restrict__ part,
                                               unsigned* __restrict__ bsum) {
    __shared__ unsigned s[256];
    const int t = threadIdx.x;
    const int i = blockIdx.x * 256 + t;
    const unsigned v = (i < NN) ? deg[i] : 0u;
    s[t] = v;
    __syncthreads();
    for (int off = 1; off < 256; off <<= 1) {
        const unsigned tmp = (t >= off) ? s[t - off] : 0u;
        __syncthreads();
        s[t] += tmp;
        __syncthreads();
    }
    if (i < NN) part[i] = s[t] - v;            // exclusive
    if (t == 255) bsum[blockIdx.x] = s[255];
}

__global__ __launch_bounds__(512) void scan2_k(const unsigned* __restrict__ bsum,
                                               unsigned* __restrict__ bscan) {
    __shared__ unsigned s[512];
    const int t = threadIdx.x;
    const unsigned v = (t < NB1) ? bsum[t] : 0u;
    s[t] = v;
    __syncthreads();
    for (int off = 1; off < 512; off <<= 1) {
        const unsigned tmp = (t >= off) ? s[t - off] : 0u;
        __syncthreads();
        s[t] += tmp;
        __syncthreads();
    }
    if (t < NB1) bscan[t] = s[t] - v;          // exclusive
}

__global__ __launch_bounds__(256) void scan3_k(const unsigned* __restrict__ part,
                                               const unsigned* __restrict__ bscan,
                                               unsigned* __restrict__ cursor) {
    const int i = blockIdx.x * 256 + threadIdx.x;
    if (i < NN) cursor[i] = part[i] + bscan[blockIdx.x];
}

__global__ __launch_bounds__(256) void place_k(const int* __restrict__ src,
                                               const int* __restrict__ dst,
                                               const float* __restrict__ ew,
                                               unsigned* __restrict__ cursor,
                                               uint2* __restrict__ pairs) {
    const int e = blockIdx.x * 256 + threadIdx.x;   // grid covers NE exactly
    const int d = dst[e];
    const unsigned p = atomicAdd(&cursor[d], 1u);
    pairs[p] = make_uint2((unsigned)src[e], __float_as_uint(ew[e]));
}

// ---- Segment sum, 4-edge-parallel: one wave per node --------------------
// lane l: edge slot g = l>>4 (4 edges per iteration), channels 4*(l&15)..+3.
// One float4 load/lane fetches 4 edge-rows per iteration (16 lanes x 16B =
// 256B coalesced per row) -> 4x fewer serial gather steps than lane=channel.
// Epilogue: shfl_xor(16,32) reduces edge slots; lanes 0..15 write float4.
__global__ __launch_bounds__(256) void segsum_k(const float* __restrict__ h,
                                                const uint2* __restrict__ pairs,
                                                const unsigned* __restrict__ cursor,
                                                const unsigned* __restrict__ deg,
                                                float* __restrict__ hnew) {
    const int node = blockIdx.x * 4 + (threadIdx.x >> 6);   // 25000*4 == NN
    const int lane = threadIdx.x & 63;
    const unsigned end = cursor[node];
    const unsigned len = deg[node];
    const unsigned start = end - len;
    const unsigned g = (unsigned)(lane >> 4);   // edge slot 0..3
    const int c4 = (lane & 15) << 2;            // channel base

    float4 acc = make_float4(0.f, 0.f, 0.f, 0.f);
    for (unsigned base = start; base < end; base += 4) {
        const unsigned e = base + g;
        if (e < end) {
            const uint2 pr = pairs[e];          // 16-lane broadcast load
            const float w = __uint_as_float(pr.y);
            const float4 hv = *(const float4*)(h + ((size_t)pr.x << 6) + c4);
            acc.x = fmaf(w, hv.x, acc.x);
            acc.y = fmaf(w, hv.y, acc.y);
            acc.z = fmaf(w, hv.z, acc.z);
            acc.w = fmaf(w, hv.w, acc.w);
        }
    }
    // reduce the 4 edge slots (lane = c + 16*g; xor bits 4,5 sum over g)
    #pragma unroll
    for (int off = 16; off < 64; off <<= 1) {
        acc.x += __shfl_xor(acc.x, off);
        acc.y += __shfl_xor(acc.y, off);
        acc.z += __shfl_xor(acc.z, off);
        acc.w += __shfl_xor(acc.w, off);
    }
    if (lane < 16) *(float4*)(hnew + ((size_t)node << 6) + c4) = acc;
}

// ---- Weight prep: pack Wih/Whh into MFMA B-fragment order (bf16) --------
__global__ __launch_bounds__(256) void wprep_k(const float* __restrict__ Wih,
                                               const float* __restrict__ Whh,
                                               unsigned* __restrict__ wfrag) {
    const int idx = blockIdx.x * 256 + threadIdx.x;  // 24 blocks * 256 = 6144
    const int row = idx >> 5;        // W row (= output col), 0..191
    const int k2  = idx & 31;        // k/2
    const int ct  = row >> 4;
    const int c   = row & 15;
    const int ks  = k2 >> 4;
    const int lhi = (k2 >> 2) & 3;   // (k>>3)&3
    const int lane = c + (lhi << 4);
    const int slot = k2 & 3;         // (k&7)>>1
    const int fo = (((ct << 1) + ks) << 8) + (lane << 2) + slot;
    const float2 wi = *(const float2*)(Wih + (row << 6) + (k2 << 1));
    const float2 wh = *(const float2*)(Whh + (row << 6) + (k2 << 1));
    wfrag[fo]            = bf16rne(wi.x) | (bf16rne(wi.y) << 16);
    wfrag[24 * 256 + fo] = bf16rne(wh.x) | (bf16rne(wh.y) << 16);
}

// ---- GRU cell via MFMA --------------------------------------------------
// One wave per 16-node group; 96 mfma_f32_16x16x32_bf16 per wave; no LDS.
// C layout (m89): col = lane&15, row = 4*(lane>>4) + reg.
__global__ __launch_bounds__(256) void gru_k(
    const float* hnew, const float* __restrict__ h,
    const unsigned* __restrict__ wfrag,
    const float* __restrict__ bih, const float* __restrict__ bhh,
    float* out)
{
    const int tid  = threadIdx.x;
    const int wid  = tid >> 6;
    const int lane = tid & 63;
    const int grp  = blockIdx.x * 4 + wid;
    if (grp >= NGRP) return;
    const int base = grp << 4;

    const int rA   = lane & 15;
    const int koff = (lane >> 4) << 3;

    const float* xr = hnew + ((base + rA) << 6);
    const float* hr = h    + ((base + rA) << 6);

    short8_t ax[2], ah[2];
    #pragma unroll
    for (int ks = 0; ks < 2; ++ks) {
        const float4 x0 = *(const float4*)(xr + ks * 32 + koff);
        const float4 x1 = *(const float4*)(xr + ks * 32 + koff + 4);
        const float4 h0 = *(const float4*)(hr + ks * 32 + koff);
        const float4 h1 = *(const float4*)(hr + ks * 32 + koff + 4);
        ax[ks] = pack8(x0, x1);
        ah[ks] = pack8(h0, h1);
    }

    f32x4 acc[24];
    #pragma unroll
    for (int i = 0; i < 24; ++i) acc[i] = (f32x4){0.f, 0.f, 0.f, 0.f};

    const unsigned* wf = wfrag + (lane << 2);
    #pragma unroll
    for (int ct = 0; ct < 12; ++ct) {
        const short8_t b0 = *(const short8_t*)(wf + (((ct << 1)     ) << 8));
        const short8_t b1 = *(const short8_t*)(wf + (((ct << 1) + 1) << 8));
        const short8_t c0 = *(const short8_t*)(wf + ((24 + (ct << 1)    ) << 8));
        const short8_t c1 = *(const short8_t*)(wf + ((24 + (ct << 1) + 1) << 8));
        acc[ct]      = __builtin_amdgcn_mfma_f32_16x16x32_bf16(ax[0], b0, acc[ct],      0, 0, 0);
        acc[ct]      = __builtin_amdgcn_mfma_f32_16x16x32_bf16(ax[1], b1, acc[ct],      0, 0, 0);
        acc[12 + ct] = __builtin_amdgcn_mfma_f32_16x16x32_bf16(ah[0], c0, acc[12 + ct], 0, 0, 0);
        acc[12 + ct] = __builtin_amdgcn_mfma_f32_16x16x32_bf16(ah[1], c1, acc[12 + ct], 0, 0, 0);
    }

    const int rnode = base + ((lane >> 4) << 2);
    const int c     = lane & 15;
    #pragma unroll
    for (int ct = 0; ct < 4; ++ct) {
        const int ch = (ct << 4) + c;
        const float brz = bih[ch] + bhh[ch];
        const float bzz = bih[64 + ch] + bhh[64 + ch];
        const float bin = bih[128 + ch];
        const float bhn = bhh[128 + ch];
        #pragma unroll
        for (int r = 0; r < 4; ++r) {
            const int node = rnode + r;
            const float rr = fsig(acc[ct][r] + acc[12 + ct][r] + brz);
            const float zz = fsig(acc[4 + ct][r] + acc[16 + ct][r] + bzz);
            const float hn = acc[20 + ct][r] + bhn;
            const float nn = ftanh(fmaf(rr, hn, acc[8 + ct][r] + bin));
            const float hv = h[(node << 6) + ch];
            out[(node << 6) + ch] = fmaf(zz, hv - nn, nn);  // (1-z)*n + z*h
        }
    }
}

extern "C" void kernel_launch(void* const* d_in, const int* in_sizes, int n_in,
                              void* d_out, int out_size, void* d_ws, size_t ws_size,
                              hipStream_t stream)
{
    const float* h   = (const float*)d_in[0];
    const float* ew  = (const float*)d_in[1];
    const float* Wih = (const float*)d_in[2];
    const float* Whh = (const float*)d_in[3];
    const float* bih = (const float*)d_in[4];
    const float* bhh = (const float*)d_in[5];
    const int*   src = (const int*)d_in[6];
    const int*   dst = (const int*)d_in[7];
    float* out = (float*)d_out;

    // ws layout (~14.05 MB)
    char* ws = (char*)d_ws;
    unsigned* deg    = (unsigned*)(ws);                 // 400,000 B
    unsigned* cursor = (unsigned*)(ws + 400000);        // 400,000 B
    unsigned* part   = (unsigned*)(ws + 800000);        // 400,000 B
    unsigned* bsum   = (unsigned*)(ws + 1200000);       //   2,048 B
    unsigned* bscan  = (unsigned*)(ws + 1202048);       //   2,048 B
    uint2*    pairs  = (uint2*)   (ws + 1204224);       // 12.8 MB
    unsigned* wfrag  = (unsigned*)(ws + 14004224);      // 49,152 B

    hipMemsetAsync(deg, 0, NN * sizeof(unsigned), stream);
    wprep_k<<<24, 256, 0, stream>>>(Wih, Whh, wfrag);
    hist_k <<<NE / 256, 256, 0, stream>>>(dst, deg);
    scan1_k<<<NB1, 256, 0, stream>>>(deg, part, bsum);
    scan2_k<<<1, 512, 0, stream>>>(bsum, bscan);
    scan3_k<<<NB1, 256, 0, stream>>>(part, bscan, cursor);
    place_k<<<NE / 256, 256, 0, stream>>>(src, dst, ew, cursor, pairs);
    segsum_k<<<NN / 4, 256, 0, stream>>>(h, pairs, cursor, deg, out); // out = hnew
    gru_k  <<<NBGRU, 256, 0, stream>>>(out, h, wfrag, bih, bhh, out);
}

// Round 12
// 218.756 us; speedup vs baseline: 3.9939x; 1.7673x over previous
//
#include <hip/hip_runtime.h>

#define NN 100000
#define NE 1600000
#define DD 64
#define NGRP 6250   // NN/16
#define NBGRU 1563  // ceil(NGRP/4)
#define NBKT 391    // buckets of 256 dst nodes (ceil(NN/256))
#define BCAP 4608   // per-bucket capacity: mean 4092, sd 64 -> +8 sigma (HW-validated r9)
#define BCH  4096   // edges per bin_k block
#define NBIN 391    // ceil(NE/BCH)
#define OVCAP 4096  // overflow capacity (never hit in practice)

typedef __attribute__((ext_vector_type(8))) short short8_t;
typedef __attribute__((ext_vector_type(4))) float f32x4;

__device__ __forceinline__ float fsig(float x) {
    return __fdividef(1.0f, 1.0f + __expf(-x));
}
__device__ __forceinline__ float ftanh(float x) {
    return __fdividef(2.0f, 1.0f + __expf(-2.0f * x)) - 1.0f;
}
__device__ __forceinline__ unsigned int bf16rne(float a) {
    unsigned int u = __float_as_uint(a);
    return (u + 0x7fffu + ((u >> 16) & 1u)) >> 16;
}
__device__ __forceinline__ short8_t pack8(float4 a, float4 b) {
    short8_t r;
    r[0] = (short)bf16rne(a.x); r[1] = (short)bf16rne(a.y);
    r[2] = (short)bf16rne(a.z); r[3] = (short)bf16rne(a.w);
    r[4] = (short)bf16rne(b.x); r[5] = (short)bf16rne(b.y);
    r[6] = (short)bf16rne(b.z); r[7] = (short)bf16rne(b.w);
    return r;
}

// ---- bin_k: LDS-staged bucket binning, 512 threads (8 waves) ------------
// Bucket b = dst>>8. Payload (src | dlocal<<17, w). Per 4096-edge chunk:
// count -> LDS scan -> stage ordered by bucket -> one global atomicAdd per
// bucket -> coalesced flush (runs of ~10 edges back-to-back => lines merge
// in L2; write traffic ~= payload, vs 8x amplification of direct scatter).
// 512 threads: 391 blocks x 8 waves ~= 12 waves/CU (the round-9 4-wave
// version was latency-starved).
__global__ __launch_bounds__(512) void bin_k(const int* __restrict__ src,
                                             const int* __restrict__ dst,
                                             const float* __restrict__ ew,
                                             unsigned* __restrict__ gcnt,
                                             uint2* __restrict__ binbuf,
                                             unsigned* __restrict__ ovcnt,
                                             uint2* __restrict__ ov_a,
                                             unsigned* __restrict__ ov_b) {
    __shared__ unsigned cnt[NBKT];
    __shared__ unsigned cur[NBKT];
    __shared__ unsigned offb[NBKT];
    __shared__ unsigned gbase[NBKT];
    __shared__ unsigned ssc[512];
    __shared__ uint2 stage[BCH];
    __shared__ unsigned short sbkt[BCH];

    const int t = threadIdx.x;
    const int e0 = blockIdx.x * BCH;
    const int M = min(BCH, NE - e0);

    for (int i = t; i < NBKT; i += 512) cnt[i] = 0;
    __syncthreads();

    // pass 1: count
    for (int i = t; i < M; i += 512) {
        const unsigned b = ((unsigned)dst[e0 + i]) >> 8;
        atomicAdd(&cnt[b], 1u);
    }
    __syncthreads();

    // exclusive scan over 391 bucket counts, width-512 Hillis-Steele
    {
        const unsigned v = (t < NBKT) ? cnt[t] : 0u;
        ssc[t] = v;
        __syncthreads();
        for (int o = 1; o < 512; o <<= 1) {
            const unsigned tmp = (t >= o) ? ssc[t - o] : 0u;
            __syncthreads();
            ssc[t] += tmp;
            __syncthreads();
        }
        if (t < NBKT) { offb[t] = ssc[t] - v; cur[t] = ssc[t] - v; }
    }
    __syncthreads();

    // pass 2: re-read edges (L2-hot), place into stage ordered by bucket
    for (int i = t; i < M; i += 512) {
        const int d = dst[e0 + i];
        const unsigned b = ((unsigned)d) >> 8;
        const unsigned p = atomicAdd(&cur[b], 1u);
        stage[p] = make_uint2((unsigned)src[e0 + i] | (((unsigned)(d & 255)) << 17),
                              __float_as_uint(ew[e0 + i]));
        sbkt[p] = (unsigned short)b;
    }
    __syncthreads();

    // per-bucket global base
    for (int i = t; i < NBKT; i += 512) {
        const unsigned c = cnt[i];
        gbase[i] = c ? atomicAdd(&gcnt[i], c) : 0u;
    }
    __syncthreads();

    // coalesced flush
    for (int i = t; i < M; i += 512) {
        const unsigned b = sbkt[i];
        const unsigned gp = gbase[b] + ((unsigned)i - offb[b]);
        if (gp < BCAP) {
            binbuf[b * BCAP + gp] = stage[i];
        } else {                                    // ~never: +8 sigma margin
            const unsigned op = atomicAdd(ovcnt, 1u);
            if (op < OVCAP) { ov_a[op] = stage[i]; ov_b[op] = b; }
        }
    }
}

// ---- sort_k: in-place exact sort within each bucket + CSR emit ----------
// One block (512 threads) per bucket. LDS histogram of dlocal -> scan ->
// scatter into LDS stage -> coalesced flush back into the SAME binbuf
// region (all reads complete before the flush). Emits cursor[node]=segment
// end (absolute) and deg[node], replacing hist/scan1-3 entirely. All
// global traffic for a bucket stays within one block/XCD -> L2-merged.
__global__ __launch_bounds__(512) void sort_k(uint2* __restrict__ binbuf,
                                              const unsigned* __restrict__ gcnt,
                                              const unsigned* __restrict__ ovcnt,
                                              const uint2* __restrict__ ov_a,
                                              const unsigned* __restrict__ ov_b,
                                              unsigned* __restrict__ cursor,
                                              unsigned* __restrict__ deg) {
    __shared__ unsigned hcnt[256];
    __shared__ unsigned off[256];
    __shared__ unsigned cur[256];
    __shared__ unsigned ssc[256];
    __shared__ uint2 stage[BCAP];   // 36,864 B

    const int t = threadIdx.x;
    const int b = blockIdx.x;
    const unsigned base = (unsigned)b * BCAP;
    const unsigned cnt = min(gcnt[b], (unsigned)BCAP);
    const unsigned oc = min(*ovcnt, (unsigned)OVCAP);

    if (t < 256) hcnt[t] = 0;
    __syncthreads();

    // pass 1: histogram of dlocal
    for (unsigned i = t; i < cnt; i += 512)
        atomicAdd(&hcnt[binbuf[base + i].x >> 17], 1u);
    for (unsigned i = t; i < oc; i += 512)
        if (ov_b[i] == (unsigned)b) atomicAdd(&hcnt[ov_a[i].x >> 17], 1u);
    __syncthreads();

    // exclusive scan of 256 counts (width-256, all 512 threads at barriers)
    unsigned v = 0;
    if (t < 256) { v = hcnt[t]; ssc[t] = v; }
    __syncthreads();
    for (int o = 1; o < 256; o <<= 1) {
        unsigned tmp = 0;
        if (t < 256 && t >= o) tmp = ssc[t - o];
        __syncthreads();
        if (t < 256) ssc[t] += tmp;
        __syncthreads();
    }
    if (t < 256) { off[t] = ssc[t] - v; cur[t] = ssc[t] - v; }
    __syncthreads();

    // emit CSR: cursor[node] = absolute segment END, deg[node]
    const int nb = min(256, NN - b * 256);
    if (t < nb) {
        const int node = b * 256 + t;
        deg[node] = hcnt[t];
        cursor[node] = base + off[t] + hcnt[t];
    }

    // pass 2: scatter into LDS stage at sorted positions
    for (unsigned i = t; i < cnt; i += 512) {
        const uint2 pr = binbuf[base + i];
        const unsigned p = atomicAdd(&cur[pr.x >> 17], 1u);
        if (p < (unsigned)BCAP) stage[p] = pr;
    }
    for (unsigned i = t; i < oc; i += 512) {
        if (ov_b[i] == (unsigned)b) {
            const uint2 pr = ov_a[i];
            const unsigned p = atomicAdd(&cur[pr.x >> 17], 1u);
            if (p < (unsigned)BCAP) stage[p] = pr;
        }
    }
    __syncthreads();

    // pass 3: coalesced flush back (in-place; reads are done)
    const unsigned tot = min(ssc[255], (unsigned)BCAP);  // inclusive total
    for (unsigned i = t; i < tot; i += 512)
        binbuf[base + i] = stage[i];
}

// ---- Segment sum, 4-edge-parallel: one wave per node --------------------
// lane l: edge slot g = l>>4, channels 4*(l&15)..+3. One float4/lane
// fetches 4 edge-rows per iteration (16 lanes x 16B = 256B coalesced/row).
// Epilogue: shfl_xor(16,32) reduces edge slots; lanes 0..15 write float4.
// (Measured: part of the 386us run.)
__global__ __launch_bounds__(256) void segsum_k(const float* __restrict__ h,
                                                const uint2* __restrict__ pairs,
                                                const unsigned* __restrict__ cursor,
                                                const unsigned* __restrict__ deg,
                                                float* __restrict__ hnew) {
    const int node = blockIdx.x * 4 + (threadIdx.x >> 6);   // 25000*4 == NN
    const int lane = threadIdx.x & 63;
    const unsigned end = cursor[node];
    const unsigned len = deg[node];
    const unsigned start = end - len;
    const unsigned g = (unsigned)(lane >> 4);   // edge slot 0..3
    const int c4 = (lane & 15) << 2;            // channel base

    float4 acc = make_float4(0.f, 0.f, 0.f, 0.f);
    for (unsigned base = start; base < end; base += 4) {
        const unsigned e = base + g;
        if (e < end) {
            const uint2 pr = pairs[e];          // 16-lane broadcast load
            const float w = __uint_as_float(pr.y);
            const unsigned sn = pr.x & 0x1ffffu;  // src node (17 bits)
            const float4 hv = *(const float4*)(h + ((size_t)sn << 6) + c4);
            acc.x = fmaf(w, hv.x, acc.x);
            acc.y = fmaf(w, hv.y, acc.y);
            acc.z = fmaf(w, hv.z, acc.z);
            acc.w = fmaf(w, hv.w, acc.w);
        }
    }
    #pragma unroll
    for (int off = 16; off < 64; off <<= 1) {
        acc.x += __shfl_xor(acc.x, off);
        acc.y += __shfl_xor(acc.y, off);
        acc.z += __shfl_xor(acc.z, off);
        acc.w += __shfl_xor(acc.w, off);
    }
    if (lane < 16) *(float4*)(hnew + ((size_t)node << 6) + c4) = acc;
}

// ---- Weight prep: pack Wih/Whh into MFMA B-fragment order (bf16) --------
__global__ __launch_bounds__(256) void wprep_k(const float* __restrict__ Wih,
                                               const float* __restrict__ Whh,
                                               unsigned* __restrict__ wfrag) {
    const int idx = blockIdx.x * 256 + threadIdx.x;  // 24 blocks * 256 = 6144
    const int row = idx >> 5;        // W row (= output col), 0..191
    const int k2  = idx & 31;        // k/2
    const int ct  = row >> 4;
    const int c   = row & 15;
    const int ks  = k2 >> 4;
    const int lhi = (k2 >> 2) & 3;   // (k>>3)&3
    const int lane = c + (lhi << 4);
    const int slot = k2 & 3;         // (k&7)>>1
    const int fo = (((ct << 1) + ks) << 8) + (lane << 2) + slot;
    const float2 wi = *(const float2*)(Wih + (row << 6) + (k2 << 1));
    const float2 wh = *(const float2*)(Whh + (row << 6) + (k2 << 1));
    wfrag[fo]            = bf16rne(wi.x) | (bf16rne(wi.y) << 16);
    wfrag[24 * 256 + fo] = bf16rne(wh.x) | (bf16rne(wh.y) << 16);
}

// ---- GRU cell via MFMA --------------------------------------------------
// One wave per 16-node group; 96 mfma_f32_16x16x32_bf16 per wave; no LDS.
// C layout (m89): col = lane&15, row = 4*(lane>>4) + reg.
__global__ __launch_bounds__(256) void gru_k(
    const float* hnew, const float* __restrict__ h,
    const unsigned* __restrict__ wfrag,
    const float* __restrict__ bih, const float* __restrict__ bhh,
    float* out)
{
    const int tid  = threadIdx.x;
    const int wid  = tid >> 6;
    const int lane = tid & 63;
    const int grp  = blockIdx.x * 4 + wid;
    if (grp >= NGRP) return;
    const int base = grp << 4;

    const int rA   = lane & 15;
    const int koff = (lane >> 4) << 3;

    const float* xr = hnew + ((base + rA) << 6);
    const float* hr = h    + ((base + rA) << 6);

    short8_t ax[2], ah[2];
    #pragma unroll
    for (int ks = 0; ks < 2; ++ks) {
        const float4 x0 = *(const float4*)(xr + ks * 32 + koff);
        const float4 x1 = *(const float4*)(xr + ks * 32 + koff + 4);
        const float4 h0 = *(const float4*)(hr + ks * 32 + koff);
        const float4 h1 = *(const float4*)(hr + ks * 32 + koff + 4);
        ax[ks] = pack8(x0, x1);
        ah[ks] = pack8(h0, h1);
    }

    f32x4 acc[24];
    #pragma unroll
    for (int i = 0; i < 24; ++i) acc[i] = (f32x4){0.f, 0.f, 0.f, 0.f};

    const unsigned* wf = wfrag + (lane << 2);
    #pragma unroll
    for (int ct = 0; ct < 12; ++ct) {
        const short8_t b0 = *(const short8_t*)(wf + (((ct << 1)     ) << 8));
        const short8_t b1 = *(const short8_t*)(wf + (((ct << 1) + 1) << 8));
        const short8_t c0 = *(const short8_t*)(wf + ((24 + (ct << 1)    ) << 8));
        const short8_t c1 = *(const short8_t*)(wf + ((24 + (ct << 1) + 1) << 8));
        acc[ct]      = __builtin_amdgcn_mfma_f32_16x16x32_bf16(ax[0], b0, acc[ct],      0, 0, 0);
        acc[ct]      = __builtin_amdgcn_mfma_f32_16x16x32_bf16(ax[1], b1, acc[ct],      0, 0, 0);
        acc[12 + ct] = __builtin_amdgcn_mfma_f32_16x16x32_bf16(ah[0], c0, acc[12 + ct], 0, 0, 0);
        acc[12 + ct] = __builtin_amdgcn_mfma_f32_16x16x32_bf16(ah[1], c1, acc[12 + ct], 0, 0, 0);
    }

    const int rnode = base + ((lane >> 4) << 2);
    const int c     = lane & 15;
    #pragma unroll
    for (int ct = 0; ct < 4; ++ct) {
        const int ch = (ct << 4) + c;
        const float brz = bih[ch] + bhh[ch];
        const float bzz = bih[64 + ch] + bhh[64 + ch];
        const float bin = bih[128 + ch];
        const float bhn = bhh[128 + ch];
        #pragma unroll
        for (int r = 0; r < 4; ++r) {
            const int node = rnode + r;
            const float rr = fsig(acc[ct][r] + acc[12 + ct][r] + brz);
            const float zz = fsig(acc[4 + ct][r] + acc[16 + ct][r] + bzz);
            const float hn = acc[20 + ct][r] + bhn;
            const float nn = ftanh(fmaf(rr, hn, acc[8 + ct][r] + bin));
            const float hv = h[(node << 6) + ch];
            out[(node << 6) + ch] = fmaf(zz, hv - nn, nn);  // (1-z)*n + z*h
        }
    }
}

extern "C" void kernel_launch(void* const* d_in, const int* in_sizes, int n_in,
                              void* d_out, int out_size, void* d_ws, size_t ws_size,
                              hipStream_t stream)
{
    const float* h   = (const float*)d_in[0];
    const float* ew  = (const float*)d_in[1];
    const float* Wih = (const float*)d_in[2];
    const float* Whh = (const float*)d_in[3];
    const float* bih = (const float*)d_in[4];
    const float* bhh = (const float*)d_in[5];
    const int*   src = (const int*)d_in[6];
    const int*   dst = (const int*)d_in[7];
    float* out = (float*)d_out;

    // ws layout (~15.33 MB, under the 25.6 MB proven available)
    char* ws = (char*)d_ws;
    unsigned* gcnt   = (unsigned*)(ws);                     //   2,048 B (391 used)
    unsigned* ovcnt  = (unsigned*)(ws + 2048);              //      64 B
    unsigned* wfrag  = (unsigned*)(ws + 2112);              //  49,152 B
    uint2*    binbuf = (uint2*)   (ws + 65536);             // 391*4608*8 = 14,413,824 B
    uint2*    ov_a   = (uint2*)   (ws + 14479360);          //  32,768 B
    unsigned* ov_b   = (unsigned*)(ws + 14512128);          //  16,384 B
    unsigned* deg    = (unsigned*)(ws + 14528512);          // 400,000 B
    unsigned* cursor = (unsigned*)(ws + 14928512);          // 400,000 B

    hipMemsetAsync(ws, 0, 2112, stream);                    // gcnt + ovcnt
    wprep_k<<<24, 256, 0, stream>>>(Wih, Whh, wfrag);
    bin_k  <<<NBIN, 512, 0, stream>>>(src, dst, ew, gcnt, binbuf, ovcnt, ov_a, ov_b);
    sort_k <<<NBKT, 512, 0, stream>>>(binbuf, gcnt, ovcnt, ov_a, ov_b, cursor, deg);
    segsum_k<<<NN / 4, 256, 0, stream>>>(h, binbuf, cursor, deg, out); // out = hnew
    gru_k  <<<NBGRU, 256, 0, stream>>>(out, h, wfrag, bih, bhh, out);
}

// Round 13
// 215.283 us; speedup vs baseline: 4.0583x; 1.0161x over previous
//
#include <hip/hip_runtime.h>

#define NN 100000
#define NE 1600000
#define DD 64
#define NGRP 6250   // NN/16
#define NBGRU 1563  // ceil(NGRP/4)
#define NBKT 391    // buckets of 256 dst nodes (ceil(NN/256))
#define BCAP 4608   // per-bucket capacity: mean 4092, sd 64 -> +8 sigma (HW-validated r9)
#define BCH  4096   // edges per bin_k block
#define NBIN 391    // ceil(NE/BCH)
#define OVCAP 4096  // overflow capacity (never hit in practice)

typedef __attribute__((ext_vector_type(8))) short short8_t;
typedef __attribute__((ext_vector_type(4))) float f32x4;

__device__ __forceinline__ float fsig(float x) {
    return __fdividef(1.0f, 1.0f + __expf(-x));
}
__device__ __forceinline__ float ftanh(float x) {
    return __fdividef(2.0f, 1.0f + __expf(-2.0f * x)) - 1.0f;
}
__device__ __forceinline__ unsigned int bf16rne(float a) {
    unsigned int u = __float_as_uint(a);
    return (u + 0x7fffu + ((u >> 16) & 1u)) >> 16;
}
__device__ __forceinline__ short8_t pack8(float4 a, float4 b) {
    short8_t r;
    r[0] = (short)bf16rne(a.x); r[1] = (short)bf16rne(a.y);
    r[2] = (short)bf16rne(a.z); r[3] = (short)bf16rne(a.w);
    r[4] = (short)bf16rne(b.x); r[5] = (short)bf16rne(b.y);
    r[6] = (short)bf16rne(b.z); r[7] = (short)bf16rne(b.w);
    return r;
}

// ---- bin_k: LDS-staged bucket binning, 512 threads (8 waves) ------------
// (Measured in the 218.8us run; not top-5.)
__global__ __launch_bounds__(512) void bin_k(const int* __restrict__ src,
                                             const int* __restrict__ dst,
                                             const float* __restrict__ ew,
                                             unsigned* __restrict__ gcnt,
                                             uint2* __restrict__ binbuf,
                                             unsigned* __restrict__ ovcnt,
                                             uint2* __restrict__ ov_a,
                                             unsigned* __restrict__ ov_b) {
    __shared__ unsigned cnt[NBKT];
    __shared__ unsigned cur[NBKT];
    __shared__ unsigned offb[NBKT];
    __shared__ unsigned gbase[NBKT];
    __shared__ unsigned ssc[512];
    __shared__ uint2 stage[BCH];
    __shared__ unsigned short sbkt[BCH];

    const int t = threadIdx.x;
    const int e0 = blockIdx.x * BCH;
    const int M = min(BCH, NE - e0);

    for (int i = t; i < NBKT; i += 512) cnt[i] = 0;
    __syncthreads();

    for (int i = t; i < M; i += 512) {
        const unsigned b = ((unsigned)dst[e0 + i]) >> 8;
        atomicAdd(&cnt[b], 1u);
    }
    __syncthreads();

    {
        const unsigned v = (t < NBKT) ? cnt[t] : 0u;
        ssc[t] = v;
        __syncthreads();
        for (int o = 1; o < 512; o <<= 1) {
            const unsigned tmp = (t >= o) ? ssc[t - o] : 0u;
            __syncthreads();
            ssc[t] += tmp;
            __syncthreads();
        }
        if (t < NBKT) { offb[t] = ssc[t] - v; cur[t] = ssc[t] - v; }
    }
    __syncthreads();

    for (int i = t; i < M; i += 512) {
        const int d = dst[e0 + i];
        const unsigned b = ((unsigned)d) >> 8;
        const unsigned p = atomicAdd(&cur[b], 1u);
        stage[p] = make_uint2((unsigned)src[e0 + i] | (((unsigned)(d & 255)) << 17),
                              __float_as_uint(ew[e0 + i]));
        sbkt[p] = (unsigned short)b;
    }
    __syncthreads();

    for (int i = t; i < NBKT; i += 512) {
        const unsigned c = cnt[i];
        gbase[i] = c ? atomicAdd(&gcnt[i], c) : 0u;
    }
    __syncthreads();

    for (int i = t; i < M; i += 512) {
        const unsigned b = sbkt[i];
        const unsigned gp = gbase[b] + ((unsigned)i - offb[b]);
        if (gp < BCAP) {
            binbuf[b * BCAP + gp] = stage[i];
        } else {                                    // ~never: +8 sigma margin
            const unsigned op = atomicAdd(ovcnt, 1u);
            if (op < OVCAP) { ov_a[op] = stage[i]; ov_b[op] = b; }
        }
    }
}

// ---- sort_k: in-place exact sort within each bucket + CSR emit ----------
// (Measured in the 218.8us run; not top-5.)
__global__ __launch_bounds__(512) void sort_k(uint2* __restrict__ binbuf,
                                              const unsigned* __restrict__ gcnt,
                                              const unsigned* __restrict__ ovcnt,
                                              const uint2* __restrict__ ov_a,
                                              const unsigned* __restrict__ ov_b,
                                              unsigned* __restrict__ cursor,
                                              unsigned* __restrict__ deg) {
    __shared__ unsigned hcnt[256];
    __shared__ unsigned off[256];
    __shared__ unsigned cur[256];
    __shared__ unsigned ssc[256];
    __shared__ uint2 stage[BCAP];   // 36,864 B

    const int t = threadIdx.x;
    const int b = blockIdx.x;
    const unsigned base = (unsigned)b * BCAP;
    const unsigned cnt = min(gcnt[b], (unsigned)BCAP);
    const unsigned oc = min(*ovcnt, (unsigned)OVCAP);

    if (t < 256) hcnt[t] = 0;
    __syncthreads();

    for (unsigned i = t; i < cnt; i += 512)
        atomicAdd(&hcnt[binbuf[base + i].x >> 17], 1u);
    for (unsigned i = t; i < oc; i += 512)
        if (ov_b[i] == (unsigned)b) atomicAdd(&hcnt[ov_a[i].x >> 17], 1u);
    __syncthreads();

    unsigned v = 0;
    if (t < 256) { v = hcnt[t]; ssc[t] = v; }
    __syncthreads();
    for (int o = 1; o < 256; o <<= 1) {
        unsigned tmp = 0;
        if (t < 256 && t >= o) tmp = ssc[t - o];
        __syncthreads();
        if (t < 256) ssc[t] += tmp;
        __syncthreads();
    }
    if (t < 256) { off[t] = ssc[t] - v; cur[t] = ssc[t] - v; }
    __syncthreads();

    const int nb = min(256, NN - b * 256);
    if (t < nb) {
        const int node = b * 256 + t;
        deg[node] = hcnt[t];
        cursor[node] = base + off[t] + hcnt[t];
    }

    for (unsigned i = t; i < cnt; i += 512) {
        const uint2 pr = binbuf[base + i];
        const unsigned p = atomicAdd(&cur[pr.x >> 17], 1u);
        if (p < (unsigned)BCAP) stage[p] = pr;
    }
    for (unsigned i = t; i < oc; i += 512) {
        if (ov_b[i] == (unsigned)b) {
            const uint2 pr = ov_a[i];
            const unsigned p = atomicAdd(&cur[pr.x >> 17], 1u);
            if (p < (unsigned)BCAP) stage[p] = pr;
        }
    }
    __syncthreads();

    const unsigned tot = min(ssc[255], (unsigned)BCAP);
    for (unsigned i = t; i < tot; i += 512)
        binbuf[base + i] = stage[i];
}

// ---- Segment sum, 8-edge-parallel: one wave per node --------------------
// Was 4 rows in flight/wave (69us, 3.07 TB/s, VALUBusy 18% -> MLP-bound).
// Now lane l services edge slots {g, g+4} (g=l>>4) per iteration, step 8:
// 8 independent 256B row-gathers in flight per wave, two acc chains.
// Same traffic & f32 math (reassociation only).
__global__ __launch_bounds__(256) void segsum_k(const float* __restrict__ h,
                                                const uint2* __restrict__ pairs,
                                                const unsigned* __restrict__ cursor,
                                                const unsigned* __restrict__ deg,
                                                float* __restrict__ hnew) {
    const int node = blockIdx.x * 4 + (threadIdx.x >> 6);   // 25000*4 == NN
    const int lane = threadIdx.x & 63;
    const unsigned end = cursor[node];
    const unsigned len = deg[node];
    const unsigned start = end - len;
    const unsigned g = (unsigned)(lane >> 4);   // edge slot 0..3
    const int c4 = (lane & 15) << 2;            // channel base

    float4 acc  = make_float4(0.f, 0.f, 0.f, 0.f);
    float4 acc2 = make_float4(0.f, 0.f, 0.f, 0.f);
    for (unsigned base = start; base < end; base += 8) {
        const unsigned e0 = base + g;
        const unsigned e1 = base + 4 + g;
        if (e0 < end) {
            const uint2 pr = pairs[e0];
            const float w = __uint_as_float(pr.y);
            const unsigned sn = pr.x & 0x1ffffu;
            const float4 hv = *(const float4*)(h + ((size_t)sn << 6) + c4);
            acc.x = fmaf(w, hv.x, acc.x);
            acc.y = fmaf(w, hv.y, acc.y);
            acc.z = fmaf(w, hv.z, acc.z);
            acc.w = fmaf(w, hv.w, acc.w);
        }
        if (e1 < end) {
            const uint2 pr = pairs[e1];
            const float w = __uint_as_float(pr.y);
            const unsigned sn = pr.x & 0x1ffffu;
            const float4 hv = *(const float4*)(h + ((size_t)sn << 6) + c4);
            acc2.x = fmaf(w, hv.x, acc2.x);
            acc2.y = fmaf(w, hv.y, acc2.y);
            acc2.z = fmaf(w, hv.z, acc2.z);
            acc2.w = fmaf(w, hv.w, acc2.w);
        }
    }
    acc.x += acc2.x; acc.y += acc2.y; acc.z += acc2.z; acc.w += acc2.w;
    #pragma unroll
    for (int off = 16; off < 64; off <<= 1) {
        acc.x += __shfl_xor(acc.x, off);
        acc.y += __shfl_xor(acc.y, off);
        acc.z += __shfl_xor(acc.z, off);
        acc.w += __shfl_xor(acc.w, off);
    }
    if (lane < 16) *(float4*)(hnew + ((size_t)node << 6) + c4) = acc;
}

// ---- Weight prep: pack Wih/Whh into MFMA B-fragment order (bf16) --------
__global__ __launch_bounds__(256) void wprep_k(const float* __restrict__ Wih,
                                               const float* __restrict__ Whh,
                                               unsigned* __restrict__ wfrag) {
    const int idx = blockIdx.x * 256 + threadIdx.x;  // 24 blocks * 256 = 6144
    const int row = idx >> 5;        // W row (= output col), 0..191
    const int k2  = idx & 31;        // k/2
    const int ct  = row >> 4;
    const int c   = row & 15;
    const int ks  = k2 >> 4;
    const int lhi = (k2 >> 2) & 3;   // (k>>3)&3
    const int lane = c + (lhi << 4);
    const int slot = k2 & 3;         // (k&7)>>1
    const int fo = (((ct << 1) + ks) << 8) + (lane << 2) + slot;
    const float2 wi = *(const float2*)(Wih + (row << 6) + (k2 << 1));
    const float2 wh = *(const float2*)(Whh + (row << 6) + (k2 << 1));
    wfrag[fo]            = bf16rne(wi.x) | (bf16rne(wi.y) << 16);
    wfrag[24 * 256 + fo] = bf16rne(wh.x) | (bf16rne(wh.y) << 16);
}

// ---- GRU cell via MFMA --------------------------------------------------
// One wave per 16-node group; 96 mfma_f32_16x16x32_bf16 per wave; no LDS.
// C layout (m89): col = lane&15, row = 4*(lane>>4) + reg.
__global__ __launch_bounds__(256) void gru_k(
    const float* hnew, const float* __restrict__ h,
    const unsigned* __restrict__ wfrag,
    const float* __restrict__ bih, const float* __restrict__ bhh,
    float* out)
{
    const int tid  = threadIdx.x;
    const int wid  = tid >> 6;
    const int lane = tid & 63;
    const int grp  = blockIdx.x * 4 + wid;
    if (grp >= NGRP) return;
    const int base = grp << 4;

    const int rA   = lane & 15;
    const int koff = (lane >> 4) << 3;

    const float* xr = hnew + ((base + rA) << 6);
    const float* hr = h    + ((base + rA) << 6);

    short8_t ax[2], ah[2];
    #pragma unroll
    for (int ks = 0; ks < 2; ++ks) {
        const float4 x0 = *(const float4*)(xr + ks * 32 + koff);
        const float4 x1 = *(const float4*)(xr + ks * 32 + koff + 4);
        const float4 h0 = *(const float4*)(hr + ks * 32 + koff);
        const float4 h1 = *(const float4*)(hr + ks * 32 + koff + 4);
        ax[ks] = pack8(x0, x1);
        ah[ks] = pack8(h0, h1);
    }

    f32x4 acc[24];
    #pragma unroll
    for (int i = 0; i < 24; ++i) acc[i] = (f32x4){0.f, 0.f, 0.f, 0.f};

    const unsigned* wf = wfrag + (lane << 2);
    #pragma unroll
    for (int ct = 0; ct < 12; ++ct) {
        const short8_t b0 = *(const short8_t*)(wf + (((ct << 1)     ) << 8));
        const short8_t b1 = *(const short8_t*)(wf + (((ct << 1) + 1) << 8));
        const short8_t c0 = *(const short8_t*)(wf + ((24 + (ct << 1)    ) << 8));
        const short8_t c1 = *(const short8_t*)(wf + ((24 + (ct << 1) + 1) << 8));
        acc[ct]      = __builtin_amdgcn_mfma_f32_16x16x32_bf16(ax[0], b0, acc[ct],      0, 0, 0);
        acc[ct]      = __builtin_amdgcn_mfma_f32_16x16x32_bf16(ax[1], b1, acc[ct],      0, 0, 0);
        acc[12 + ct] = __builtin_amdgcn_mfma_f32_16x16x32_bf16(ah[0], c0, acc[12 + ct], 0, 0, 0);
        acc[12 + ct] = __builtin_amdgcn_mfma_f32_16x16x32_bf16(ah[1], c1, acc[12 + ct], 0, 0, 0);
    }

    const int rnode = base + ((lane >> 4) << 2);
    const int c     = lane & 15;
    #pragma unroll
    for (int ct = 0; ct < 4; ++ct) {
        const int ch = (ct << 4) + c;
        const float brz = bih[ch] + bhh[ch];
        const float bzz = bih[64 + ch] + bhh[64 + ch];
        const float bin = bih[128 + ch];
        const float bhn = bhh[128 + ch];
        #pragma unroll
        for (int r = 0; r < 4; ++r) {
            const int node = rnode + r;
            const float rr = fsig(acc[ct][r] + acc[12 + ct][r] + brz);
            const float zz = fsig(acc[4 + ct][r] + acc[16 + ct][r] + bzz);
            const float hn = acc[20 + ct][r] + bhn;
            const float nn = ftanh(fmaf(rr, hn, acc[8 + ct][r] + bin));
            const float hv = h[(node << 6) + ch];
            out[(node << 6) + ch] = fmaf(zz, hv - nn, nn);  // (1-z)*n + z*h
        }
    }
}

extern "C" void kernel_launch(void* const* d_in, const int* in_sizes, int n_in,
                              void* d_out, int out_size, void* d_ws, size_t ws_size,
                              hipStream_t stream)
{
    const float* h   = (const float*)d_in[0];
    const float* ew  = (const float*)d_in[1];
    const float* Wih = (const float*)d_in[2];
    const float* Whh = (const float*)d_in[3];
    const float* bih = (const float*)d_in[4];
    const float* bhh = (const float*)d_in[5];
    const int*   src = (const int*)d_in[6];
    const int*   dst = (const int*)d_in[7];
    float* out = (float*)d_out;

    // ws layout (~15.33 MB, under the 25.6 MB proven available)
    char* ws = (char*)d_ws;
    unsigned* gcnt   = (unsigned*)(ws);                     //   2,048 B (391 used)
    unsigned* ovcnt  = (unsigned*)(ws + 2048);              //      64 B
    unsigned* wfrag  = (unsigned*)(ws + 2112);              //  49,152 B
    uint2*    binbuf = (uint2*)   (ws + 65536);             // 391*4608*8 = 14,413,824 B
    uint2*    ov_a   = (uint2*)   (ws + 14479360);          //  32,768 B
    unsigned* ov_b   = (unsigned*)(ws + 14512128);          //  16,384 B
    unsigned* deg    = (unsigned*)(ws + 14528512);          // 400,000 B
    unsigned* cursor = (unsigned*)(ws + 14928512);          // 400,000 B

    hipMemsetAsync(ws, 0, 2112, stream);                    // gcnt + ovcnt
    wprep_k<<<24, 256, 0, stream>>>(Wih, Whh, wfrag);
    bin_k  <<<NBIN, 512, 0, stream>>>(src, dst, ew, gcnt, binbuf, ovcnt, ov_a, ov_b);
    sort_k <<<NBKT, 512, 0, stream>>>(binbuf, gcnt, ovcnt, ov_a, ov_b, cursor, deg);
    segsum_k<<<NN / 4, 256, 0, stream>>>(h, binbuf, cursor, deg, out); // out = hnew
    gru_k  <<<NBGRU, 256, 0, stream>>>(out, h, wfrag, bih, bhh, out);
}